// Round 9
// baseline (158.097 us; speedup 1.0000x reference)
//
#include <hip/hip_runtime.h>

// SSIM loss v16: LDS-free loop -- per-lane direct global windows.
// 8-round invariant map: occupancy x2 (v9), VALU -11% (v10/v11), LDS bytes
// -45% (v13), prefetch depth 2 (v10), LDS double-buffer (v15) ALL leave
// step time at ~730-746 cyc, 43% VALU-idle. Last untested shared property:
// every variant couples all lanes through LDS each step (stage->fence->read),
// re-synchronizing the 12 resident waves into lockstep so their stall
// windows overlap and TLP cannot fill them.
// v16 removes LDS from the loop: each lane loads its own 11-col window
// straight from global (3 overlapping dwordx4 per image; 4B alignment is
// legal for global_load_dwordx4 on CDNA; L1/L2/L3 absorb the ~10x overlap
// since inputs are L3-resident). Image edges fold into a per-lane
// precomputed masked-weight vector wgm[12] (base clamp + shifted weight
// index), so the step body has zero masking cost and zero branches.
// Vertical ring / retire / shift byte-identical to v12.
// Predicted: conflicts 0, VGPR ~140-155 (WRITE ~24KB tripwire; <=170 keeps
// 3 w/SIMD), success = VALUBusy 70-85% & kernel 45-55us; failure = ~70us
// flat VALUBusy => VMEM pipe is the wall (localized).

#define BATCH  16
#define CHAN   3
#define H_     512
#define W_     512
#define HW     (H_ * W_)
#define CH_H   64
#define NSTEP  (CH_H + 10)          // 74
#define NPIX   ((long)BATCH*CHAN*H_*W_)

// Normalized 11-tap Gaussian, sigma=1.5 (constants gave absmax 0 in v1/v2/v6).
#define GW0 0.0010284f
#define GW1 0.0075988f
#define GW2 0.0360008f
#define GW3 0.1093554f
#define GW4 0.2130056f
#define GW5 0.2660117f

typedef float v2  __attribute__((ext_vector_type(2)));
typedef float v4f __attribute__((ext_vector_type(4)));

__device__ __forceinline__ v2 pfma(v2 a, v2 b, v2 c) {
#if __has_builtin(__builtin_elementwise_fma)
    return __builtin_elementwise_fma(a, b, c);
#else
    v2 r; r.x = fmaf(a.x, b.x, c.x); r.y = fmaf(a.y, b.y, c.y); return r;
#endif
}
__device__ __forceinline__ v2 psfma(float s, v2 b, v2 c) {  // (s,s)*b + c
    v2 sv; sv.x = s; sv.y = s;
    return pfma(sv, b, c);
}

__device__ __forceinline__ float wgk(int k) {  // k literal -> constant
    return (k == 0 || k == 10) ? GW0
         : (k == 1 || k == 9)  ? GW1
         : (k == 2 || k == 8)  ? GW2
         : (k == 3 || k == 7)  ? GW3
         : (k == 4 || k == 6)  ? GW4 : GW5;
}

__device__ __forceinline__ float ssim_retire(float mu1, float mu2,
                                             float x11, float x22, float x12) {
    const float c1 = 1.0e-4f;
    const float c2 = 9.0e-4f;
    float mu1s = mu1 * mu1;
    float mu2s = mu2 * mu2;
    float m12  = mu1 * mu2;
    float num  = (2.0f * m12 + c1) * (2.0f * (x12 - m12) + c2);
    float den  = (mu1s + mu2s + c1) * ((x11 - mu1s) + (x22 - mu2s) + c2);
#if __has_builtin(__builtin_amdgcn_rcpf)
    float l = 1.0f - num * __builtin_amdgcn_rcpf(den);   // v_rcp_f32, ~1 ulp
#else
    float l = 1.0f - num / den;
#endif
    return fminf(fmaxf(l, 0.0f), 1.0f);
}

// Slot i state: P=(mu1,mu2) packed, Q=(x11,x22) packed, E=x12 scalar.
#define DECL(i) v2 P##i = {0.f, 0.f}, Q##i = {0.f, 0.f}; float E##i = 0.f
#define ACCI(i) do { const float wj_ = wgk(10 - (i));            \
    P##i = psfma(wj_, hmm, P##i);                                \
    Q##i = psfma(wj_, hss, Q##i);                                \
    E##i = fmaf(wj_, hmx, E##i); } while (0)
#define SHIFT(i, j) P##i = P##j; Q##i = Q##j; E##i = E##j

// Extract float j (literal) from a 12-float window held in 3 v4f regs.
#define EL(a_, b_, c_, j_) ((j_) < 4 ? (a_)[(j_) & 3]                 \
                          : (j_) < 8 ? (b_)[(j_) & 3] : (c_)[(j_) & 3])

__global__ __launch_bounds__(256) void ssim_kernel(const float* __restrict__ img1,
                                                   const float* __restrict__ img2,
                                                   float* __restrict__ out) {
    __shared__ float wsum[4];

    const int tid  = threadIdx.x;
    const int lane = tid & 63;
    const int wv   = tid >> 6;

    const int wid   = blockIdx.x * 4 + wv;     // 0..3071
    const int plane = wid >> 6;
    const int rem   = wid & 63;
    const int strip = rem & 7;
    const int chunk = rem >> 3;
    const int y0 = chunk * CH_H;
    const int c0 = strip * 64;

    // Lane owns output col (c0+lane); window cols bc..bc+10, bc = c0+lane-5.
    // Load base clamped to [0, W-12]; the shift s = bcc-bc is folded into the
    // weight index: float j of the loaded window has weight wg(j+s) if
    // 0<=j+s<=10 else 0. This exactly reproduces zero-padding at both edges
    // (taps outside the clamped 12-float window never map to a valid index).
    const int bc  = c0 + lane - 5;
    const int bcc = min(max(bc, 0), W_ - 12);
    const int s   = bcc - bc;                  // -6..5
    float wgm[12];
#pragma unroll
    for (int j = 0; j < 12; ++j) {
        int ki = j + s;
        float w = 0.0f;
        w = (ki == 0 || ki == 10) ? GW0 : w;
        w = (ki == 1 || ki == 9)  ? GW1 : w;
        w = (ki == 2 || ki == 8)  ? GW2 : w;
        w = (ki == 3 || ki == 7)  ? GW3 : w;
        w = (ki == 4 || ki == 6)  ? GW4 : w;
        w = (ki == 5)             ? GW5 : w;
        wgm[j] = w;
    }

    const size_t pb = (size_t)plane * HW;
    const float* __restrict__ p1 = img1 + pb + bcc;
    const float* __restrict__ p2 = img2 + pb + bcc;

    DECL(0); DECL(1); DECL(2); DECL(3); DECL(4); DECL(5);
    DECL(6); DECL(7); DECL(8); DECL(9); DECL(10);
    float lsum = 0.0f;

    // Current window regs (row y0+step-5) and its row mask.
    v4f a0, a1, a2, b0, b1, b2;
    float rmC;
    {
        int r = y0 - 5;
        rmC = ((unsigned)r < (unsigned)H_) ? 1.0f : 0.0f;
        size_t off = (size_t)((unsigned)r < (unsigned)H_ ? r : 0) << 9;
        a0 = *(const v4f*)(p1 + off);
        a1 = *(const v4f*)(p1 + off + 4);
        a2 = *(const v4f*)(p1 + off + 8);
        b0 = *(const v4f*)(p2 + off);
        b1 = *(const v4f*)(p2 + off + 4);
        b2 = *(const v4f*)(p2 + off + 8);
    }

#pragma unroll 2
    for (int step = 0; step < NSTEP; ++step) {
        const int yy = step - 10;              // output row retired this step

        // 1. Prefetch next row's windows (row y0+step-4); ~1 full step of
        //    slack; independent of everything below.
        v4f na0, na1, na2, nb0, nb1, nb2;
        float rmN;
        {
            int r = y0 + step - 4;
            bool rok = (unsigned)r < (unsigned)H_;
            rmN = rok ? 1.0f : 0.0f;
            size_t off = (size_t)(rok ? r : 0) << 9;
            na0 = *(const v4f*)(p1 + off);
            na1 = *(const v4f*)(p1 + off + 4);
            na2 = *(const v4f*)(p1 + off + 8);
            nb0 = *(const v4f*)(p2 + off);
            nb1 = *(const v4f*)(p2 + off + 4);
            nb2 = *(const v4f*)(p2 + off + 8);
        }

        // 2. Horizontal 12-tap (masked weights) from registers. 5 running
        //    sums; row mask folded at the end (uniform, 5 muls).
        float hm1 = 0.f, hm2 = 0.f, hm11 = 0.f, hm22 = 0.f, hm12v = 0.f;
#pragma unroll
        for (int j = 0; j < 12; ++j) {
            float av = EL(a0, a1, a2, j);
            float bv = EL(b0, b1, b2, j);
            float wv_ = wgm[j];
            float ta = wv_ * av;
            float tb = wv_ * bv;
            hm1 += ta;
            hm2 += tb;
            hm11 = fmaf(ta, av, hm11);
            hm22 = fmaf(tb, bv, hm22);
            hm12v = fmaf(ta, bv, hm12v);
        }
        v2 hmm = {hm1 * rmC, hm2 * rmC};
        v2 hss = {hm11 * rmC, hm22 * rmC};
        float hmx = hm12v * rmC;

        // 3. Accumulate into the 11 in-flight output rows.
        ACCI(0); ACCI(1); ACCI(2); ACCI(3); ACCI(4); ACCI(5);
        ACCI(6); ACCI(7); ACCI(8); ACCI(9); ACCI(10);

        // 4. Retire output row yy (slot 0 complete).
        if (yy >= 0) lsum += ssim_retire(P0.x, P0.y, Q0.x, Q0.y, E0);

        // 5. Shift the register ring (pure SSA renames; unroll-2 elides half).
        SHIFT(0, 1); SHIFT(1, 2); SHIFT(2, 3); SHIFT(3, 4); SHIFT(4, 5);
        SHIFT(5, 6); SHIFT(6, 7); SHIFT(7, 8); SHIFT(8, 9); SHIFT(9, 10);
        P10 = (v2){0.f, 0.f}; Q10 = (v2){0.f, 0.f}; E10 = 0.f;

        // 6. Advance window pipeline (renames away under unroll-2).
        a0 = na0; a1 = na1; a2 = na2;
        b0 = nb0; b1 = nb1; b2 = nb2;
        rmC = rmN;
    }

    // Reduction: wave shuffle -> LDS -> one atomic per block.
#pragma unroll
    for (int off = 32; off > 0; off >>= 1) lsum += __shfl_down(lsum, off);
    if (lane == 0) wsum[wv] = lsum;
    __syncthreads();
    if (tid == 0) {
        float bs = wsum[0] + wsum[1] + wsum[2] + wsum[3];
        atomicAdd(out, bs * (0.5f / (float)NPIX));
    }
}

extern "C" void kernel_launch(void* const* d_in, const int* in_sizes, int n_in,
                              void* d_out, int out_size, void* d_ws, size_t ws_size,
                              hipStream_t stream) {
    const float* img1 = (const float*)d_in[0];
    const float* img2 = (const float*)d_in[1];
    float* out = (float*)d_out;

    hipMemsetAsync(out, 0, sizeof(float), stream);

    // 8 strips x 8 chunks x 48 planes = 3072 waves = 768 blocks = 3/CU.
    ssim_kernel<<<dim3(8 * 8 * BATCH * CHAN / 4), 256, 0, stream>>>(img1, img2, out);
}